// Round 8
// baseline (409.486 us; speedup 1.0000x reference)
//
#include <hip/hip_runtime.h>
#include <math.h>

#define NNODES 10000
#define HID    1024
#define NHEADS 4
#define NGRAPH 16
#define NCLS   10

typedef __attribute__((ext_vector_type(8))) short bf16x8;
typedef __attribute__((ext_vector_type(8))) ushort u16x8;
typedef __attribute__((ext_vector_type(4))) float f32x4;

__device__ __forceinline__ ushort bf16r(float f) {
    union { float f; unsigned u; } x; x.f = f;
    unsigned r = x.u + 0x7FFFu + ((x.u >> 16) & 1u);
    return (ushort)(r >> 16);
}
__device__ __forceinline__ float bf16f(ushort u) {
    union { unsigned u; float f; } x; x.u = ((unsigned)u) << 16;
    return x.f;
}
__device__ __forceinline__ float leaky(float e) { return e > 0.f ? e : 0.2f * e; }

// ---------------- CSR build ----------------

__global__ void k_hist(const int* __restrict__ dstArr, int* __restrict__ counts, int E) {
    int e = blockIdx.x * 256 + threadIdx.x;
    int total = E + NNODES;
    if (e < total) {
        int d = (e < E) ? dstArr[e] : (e - E);   // self-loops appended
        atomicAdd(&counts[d], 1);
    }
}

__global__ __launch_bounds__(1024) void k_scan(const int* __restrict__ counts,
                                               int* __restrict__ row_ptr, int N) {
    __shared__ int lds[1024];
    int t = threadIdx.x;
    const int C = (N + 1023) / 1024;
    int base = t * C;
    int s = 0;
    for (int i = 0; i < C; ++i)
        if (base + i < N) s += counts[base + i];
    lds[t] = s;
    __syncthreads();
    for (int off = 1; off < 1024; off <<= 1) {
        int add = (t >= off) ? lds[t - off] : 0;
        __syncthreads();
        lds[t] += add;
        __syncthreads();
    }
    int run = lds[t] - s;   // exclusive prefix
    for (int i = 0; i < C; ++i) {
        if (base + i < N) {
            row_ptr[base + i] = run;
            run += counts[base + i];
        }
    }
    if (t == 1023) row_ptr[N] = lds[1023];
}

__global__ void k_scatter(const int* __restrict__ srcArr, const int* __restrict__ dstArr,
                          const int* __restrict__ row_ptr, int* __restrict__ fill,
                          int* __restrict__ col, int E) {
    int e = blockIdx.x * 256 + threadIdx.x;
    int total = E + NNODES;
    if (e < total) {
        int s, d;
        if (e < E) { s = srcArr[e]; d = dstArr[e]; }
        else       { s = d = e - E; }
        int pos = row_ptr[d] + atomicAdd(&fill[d], 1);
        col[pos] = s;
    }
}

// ---------------- conversions ----------------

__global__ void k_f32_to_bf16(const float* __restrict__ in, ushort* __restrict__ out, int n4) {
    int i = blockIdx.x * 256 + threadIdx.x;
    if (i < n4) {
        float4 v = ((const float4*)in)[i];
        ushort4 o;
        o.x = bf16r(v.x); o.y = bf16r(v.y); o.z = bf16r(v.z); o.w = bf16r(v.w);
        ((ushort4*)out)[i] = o;
    }
}

// W [K][1024] f32 -> Wt [1024][K] bf16
__global__ __launch_bounds__(256) void k_wT(const float* __restrict__ W, ushort* __restrict__ Wt, int K) {
    __shared__ ushort tile[32][33];
    int bx = blockIdx.x;              // along N (1024/32)
    int by = blockIdx.y;              // along K
    int tx = threadIdx.x & 31, ty = threadIdx.x >> 5;   // 32 x 8
#pragma unroll
    for (int i = 0; i < 32; i += 8) {
        int k  = by * 32 + ty + i;
        int nn = bx * 32 + tx;
        tile[ty + i][tx] = bf16r(W[(size_t)k * HID + nn]);
    }
    __syncthreads();
#pragma unroll
    for (int i = 0; i < 32; i += 8) {
        int nn = bx * 32 + ty + i;
        int k  = by * 32 + tx;
        Wt[(size_t)nn * K + k] = tile[tx][ty + i];
    }
}

// ---------------- bf16 MFMA GEMM + fused e_src/e_dst epilogue ----------------
// C[M,1024] = A[M,K] * Bt[1024,K]^T (bf16 out). 1-D grid of 8*nbm blocks,
// XCD-bijective swizzle (nwg % 8 == 0). Epilogue also accumulates
// esrc/edst[row*4+head] via 16-lane shuffle reduce + atomicAdd (head = bn>>8).

#define BM 128
#define BN 128
#define BK 64

__global__ __launch_bounds__(256) void k_gemm_bf16(const ushort* __restrict__ A,
                                                   const ushort* __restrict__ Bt,
                                                   ushort* __restrict__ C, int M, int K,
                                                   int nbm,
                                                   const float* __restrict__ asrcL,
                                                   const float* __restrict__ adstL,
                                                   float* __restrict__ esrcO,
                                                   float* __restrict__ edstO) {
    __shared__ ushort As[BM * BK];
    __shared__ ushort Bs[BN * BK];
    const int t    = threadIdx.x;
    const int lane = t & 63;
    const int w    = t >> 6;
    const int wr   = w >> 1, wc = w & 1;

    // XCD-bijective swizzle: nwg = 8*nbm, q = nbm
    const int orig = blockIdx.x;
    const int wg   = (orig & 7) * nbm + (orig >> 3);
    const int bm   = (wg >> 3) * BM;
    const int bn   = (wg & 7) * BN;

    f32x4 acc[4][4] = {};

    const int r_  = t >> 3;          // fc = i*256+t -> row = i*32 + t>>3
    const int cp_ = t & 7;           // linear chunk within row

    for (int k0 = 0; k0 < K; k0 += BK) {
        __syncthreads();             // LDS free for overwrite
#pragma unroll
        for (int i = 0; i < 4; ++i) {
            int fc = i * 256 + t;
            int r  = i * 32 + r_;
            int c  = cp_ ^ (r & 7);  // inverse-swizzled source chunk
            int ga = bm + r; if (ga >= M) ga = M - 1;
            __builtin_amdgcn_global_load_lds(
                (const __attribute__((address_space(1))) unsigned*)&A[(size_t)ga * K + k0 + c * 8],
                (__attribute__((address_space(3))) unsigned*)&As[fc * 8], 16, 0, 0);
            __builtin_amdgcn_global_load_lds(
                (const __attribute__((address_space(1))) unsigned*)&Bt[(size_t)(bn + r) * K + k0 + c * 8],
                (__attribute__((address_space(3))) unsigned*)&Bs[fc * 8], 16, 0, 0);
        }
        __syncthreads();             // staging visible (compiler drains vmcnt)

#pragma unroll
        for (int s = 0; s < 2; ++s) {
            const int kc = s * 4 + (lane >> 4);     // k-chunk index 0..7
            bf16x8 a[4], b[4];
#pragma unroll
            for (int m = 0; m < 4; ++m) {
                int row = wr * 64 + m * 16 + (lane & 15);
                int ch  = kc ^ (row & 7);
                a[m] = *(const bf16x8*)&As[row * BK + ch * 8];
            }
#pragma unroll
            for (int n = 0; n < 4; ++n) {
                int cl = wc * 64 + n * 16 + (lane & 15);
                int ch = kc ^ (cl & 7);
                b[n] = *(const bf16x8*)&Bs[cl * BK + ch * 8];
            }
#pragma unroll
            for (int m = 0; m < 4; ++m)
#pragma unroll
                for (int n = 0; n < 4; ++n)
                    acc[m][n] = __builtin_amdgcn_mfma_f32_16x16x32_bf16(a[m], b[n], acc[m][n], 0, 0, 0);
        }
    }

    // C-write. C/D layout: col = lane&15, row = (lane>>4)*4 + j   [m89-verified]
#pragma unroll
    for (int m = 0; m < 4; ++m) {
        int row0 = bm + wr * 64 + m * 16 + (lane >> 4) * 4;
#pragma unroll
        for (int n = 0; n < 4; ++n) {
            int coln = bn + wc * 64 + n * 16 + (lane & 15);
#pragma unroll
            for (int j = 0; j < 4; ++j) {
                int row = row0 + j;
                if (row < M) C[(size_t)row * HID + coln] = bf16r(acc[m][n][j]);
            }
        }
    }

    // fused e_src/e_dst: whole block lies in head (bn >> 8)
    const int hHead = bn >> 8;
    float as_[4], ad_[4];
#pragma unroll
    for (int n = 0; n < 4; ++n) {
        int coln = bn + wc * 64 + n * 16 + (lane & 15);
        as_[n] = asrcL[coln];
        ad_[n] = adstL[coln];
    }
#pragma unroll
    for (int m = 0; m < 4; ++m) {
#pragma unroll
        for (int j = 0; j < 4; ++j) {
            float ps = 0.f, pd = 0.f;
#pragma unroll
            for (int n = 0; n < 4; ++n) {
                float v = acc[m][n][j];
                ps += v * as_[n];
                pd += v * ad_[n];
            }
#pragma unroll
            for (int off = 1; off < 16; off <<= 1) {
                ps += __shfl_xor(ps, off);
                pd += __shfl_xor(pd, off);
            }
            int row = bm + wr * 64 + m * 16 + (lane >> 4) * 4 + j;
            if ((lane & 15) == 0 && row < M) {
                atomicAdd(&esrcO[row * 4 + hHead], ps);
                atomicAdd(&edstO[row * 4 + hHead], pd);
            }
        }
    }
}

// ---------------- per-edge normalized attention weights (transposed out) ----------------
// 1 wave per node, 4 nodes per block. Writes alphaT[h][csr_slot].

__global__ __launch_bounds__(256) void k_alpha(const float* __restrict__ esrc,
                                               const float* __restrict__ edst,
                                               const int* __restrict__ row_ptr,
                                               const int* __restrict__ col,
                                               float* __restrict__ alphaT, int nepad) {
    const int lane = threadIdx.x & 63;
    const int n = blockIdx.x * 4 + (threadIdx.x >> 6);
    const int beg = row_ptr[n], end = row_ptr[n + 1];
    const int deg = end - beg;
    const float4 ed = *(const float4*)&edst[n * 4];

    float e0[4], e1[4];
    const bool has0 = lane < deg;
    const bool has1 = lane + 64 < deg;
    float m0 = -1e30f, m1 = -1e30f, m2 = -1e30f, m3 = -1e30f;
    if (has0) {
        float4 es = *(const float4*)&esrc[col[beg + lane] * 4];
        e0[0] = leaky(es.x + ed.x); e0[1] = leaky(es.y + ed.y);
        e0[2] = leaky(es.z + ed.z); e0[3] = leaky(es.w + ed.w);
        m0 = e0[0]; m1 = e0[1]; m2 = e0[2]; m3 = e0[3];
    }
    if (has1) {
        float4 es = *(const float4*)&esrc[col[beg + 64 + lane] * 4];
        e1[0] = leaky(es.x + ed.x); e1[1] = leaky(es.y + ed.y);
        e1[2] = leaky(es.z + ed.z); e1[3] = leaky(es.w + ed.w);
        m0 = fmaxf(m0, e1[0]); m1 = fmaxf(m1, e1[1]);
        m2 = fmaxf(m2, e1[2]); m3 = fmaxf(m3, e1[3]);
    }
    for (int j = beg + 128 + lane; j < end; j += 64) {   // rare path
        float4 es = *(const float4*)&esrc[col[j] * 4];
        m0 = fmaxf(m0, leaky(es.x + ed.x)); m1 = fmaxf(m1, leaky(es.y + ed.y));
        m2 = fmaxf(m2, leaky(es.z + ed.z)); m3 = fmaxf(m3, leaky(es.w + ed.w));
    }
#pragma unroll
    for (int off = 32; off > 0; off >>= 1) {
        m0 = fmaxf(m0, __shfl_xor(m0, off)); m1 = fmaxf(m1, __shfl_xor(m1, off));
        m2 = fmaxf(m2, __shfl_xor(m2, off)); m3 = fmaxf(m3, __shfl_xor(m3, off));
    }
    float d0 = 0.f, d1 = 0.f, d2 = 0.f, d3 = 0.f;
    if (has0) {
        e0[0] = __expf(e0[0] - m0); e0[1] = __expf(e0[1] - m1);
        e0[2] = __expf(e0[2] - m2); e0[3] = __expf(e0[3] - m3);
        d0 += e0[0]; d1 += e0[1]; d2 += e0[2]; d3 += e0[3];
    }
    if (has1) {
        e1[0] = __expf(e1[0] - m0); e1[1] = __expf(e1[1] - m1);
        e1[2] = __expf(e1[2] - m2); e1[3] = __expf(e1[3] - m3);
        d0 += e1[0]; d1 += e1[1]; d2 += e1[2]; d3 += e1[3];
    }
    for (int j = beg + 128 + lane; j < end; j += 64) {   // rare path
        float4 es = *(const float4*)&esrc[col[j] * 4];
        d0 += __expf(leaky(es.x + ed.x) - m0); d1 += __expf(leaky(es.y + ed.y) - m1);
        d2 += __expf(leaky(es.z + ed.z) - m2); d3 += __expf(leaky(es.w + ed.w) - m3);
    }
#pragma unroll
    for (int off = 32; off > 0; off >>= 1) {
        d0 += __shfl_xor(d0, off); d1 += __shfl_xor(d1, off);
        d2 += __shfl_xor(d2, off); d3 += __shfl_xor(d3, off);
    }
    const float i0 = 1.f / d0, i1 = 1.f / d1, i2 = 1.f / d2, i3 = 1.f / d3;
    if (has0) {
        int j = beg + lane;
        alphaT[0 * nepad + j] = e0[0] * i0;
        alphaT[1 * nepad + j] = e0[1] * i1;
        alphaT[2 * nepad + j] = e0[2] * i2;
        alphaT[3 * nepad + j] = e0[3] * i3;
    }
    if (has1) {
        int j = beg + 64 + lane;
        alphaT[0 * nepad + j] = e1[0] * i0;
        alphaT[1 * nepad + j] = e1[1] * i1;
        alphaT[2 * nepad + j] = e1[2] * i2;
        alphaT[3 * nepad + j] = e1[3] * i3;
    }
    for (int j = beg + 128 + lane; j < end; j += 64) {   // rare path
        float4 es = *(const float4*)&esrc[col[j] * 4];
        alphaT[0 * nepad + j] = __expf(leaky(es.x + ed.x) - m0) * i0;
        alphaT[1 * nepad + j] = __expf(leaky(es.y + ed.y) - m1) * i1;
        alphaT[2 * nepad + j] = __expf(leaky(es.z + ed.z) - m2) * i2;
        alphaT[3 * nepad + j] = __expf(leaky(es.w + ed.w) - m3) * i3;
    }
}

// ---------------- aggregation: chunk-8 double-buffered gather ----------------
// 2 waves per node (128 threads x 8 ch), 2 nodes per 256-block.
// 8 row-gathers in flight while FMA-ing the previous 8 (~300cy VALU window).
// Macro internals use trailing-underscore names (round-6 shadowing lesson).

__global__ __launch_bounds__(256) void k_agg(const ushort* __restrict__ proj,
                                             const float* __restrict__ alphaT,
                                             const int* __restrict__ row_ptr,
                                             const int* __restrict__ col,
                                             const float* __restrict__ bias,
                                             ushort* __restrict__ hb16, int nepad) {
    const int half = threadIdx.x >> 7;
    const int nid  = blockIdx.x * 2 + half;
    const int tt   = threadIdx.x & 127;
    const int h    = tt >> 5;
    const int beg  = row_ptr[nid], end = row_ptr[nid + 1];
    const float* aT = alphaT + (size_t)h * nepad;
    const ushort* pbase = proj + tt * 8;

    float acc[8] = {};

#define LOADCHUNK(cb, A0, A1, A2, A3, V0, V1, V2, V3)                        \
    {                                                                        \
        int4   cc_ = *(const int4*)&col[cb];                                 \
        float4 aa_ = *(const float4*)&aT[cb];                                \
        bool m0_ = ((cb) + 0 >= beg) & ((cb) + 0 < end);                     \
        bool m1_ = ((cb) + 1 >= beg) & ((cb) + 1 < end);                     \
        bool m2_ = ((cb) + 2 >= beg) & ((cb) + 2 < end);                     \
        bool m3_ = ((cb) + 3 >= beg) & ((cb) + 3 < end);                     \
        int s0_ = m0_ ? cc_.x : 0; int s1_ = m1_ ? cc_.y : 0;                \
        int s2_ = m2_ ? cc_.z : 0; int s3_ = m3_ ? cc_.w : 0;                \
        A0 = m0_ ? aa_.x : 0.f; A1 = m1_ ? aa_.y : 0.f;                      \
        A2 = m2_ ? aa_.z : 0.f; A3 = m3_ ? aa_.w : 0.f;                      \
        V0 = *(const u16x8*)&pbase[(size_t)s0_ * HID];                       \
        V1 = *(const u16x8*)&pbase[(size_t)s1_ * HID];                       \
        V2 = *(const u16x8*)&pbase[(size_t)s2_ * HID];                       \
        V3 = *(const u16x8*)&pbase[(size_t)s3_ * HID];                       \
    }

#define FMACHUNK(A0, A1, A2, A3, V0, V1, V2, V3)                             \
    {                                                                        \
        _Pragma("unroll")                                                    \
        for (int i_ = 0; i_ < 8; ++i_)                                       \
            acc[i_] += A0 * bf16f(V0[i_]) + A1 * bf16f(V1[i_])               \
                     + A2 * bf16f(V2[i_]) + A3 * bf16f(V3[i_]);              \
    }

    int c = beg & ~7;
    float a0, a1, a2, a3, a4, a5, a6, a7;
    u16x8 v0, v1, v2, v3, v4, v5, v6, v7;
    LOADCHUNK(c,     a0, a1, a2, a3, v0, v1, v2, v3);
    LOADCHUNK(c + 4, a4, a5, a6, a7, v4, v5, v6, v7);
    for (c += 8; c < end; c += 8) {
        float na0, na1, na2, na3, na4, na5, na6, na7;
        u16x8 nv0, nv1, nv2, nv3, nv4, nv5, nv6, nv7;
        LOADCHUNK(c,     na0, na1, na2, na3, nv0, nv1, nv2, nv3);
        LOADCHUNK(c + 4, na4, na5, na6, na7, nv4, nv5, nv6, nv7);
        FMACHUNK(a0, a1, a2, a3, v0, v1, v2, v3);
        FMACHUNK(a4, a5, a6, a7, v4, v5, v6, v7);
        a0 = na0; a1 = na1; a2 = na2; a3 = na3;
        a4 = na4; a5 = na5; a6 = na6; a7 = na7;
        v0 = nv0; v1 = nv1; v2 = nv2; v3 = nv3;
        v4 = nv4; v5 = nv5; v6 = nv6; v7 = nv7;
    }
    FMACHUNK(a0, a1, a2, a3, v0, v1, v2, v3);
    FMACHUNK(a4, a5, a6, a7, v4, v5, v6, v7);
#undef LOADCHUNK
#undef FMACHUNK

    u16x8 o;
#pragma unroll
    for (int i = 0; i < 8; ++i) {
        float b = bias[tt * 8 + i];
        o[i] = bf16r(fmaxf(acc[i] + b, 0.f));
    }
    *(u16x8*)&hb16[(size_t)nid * HID + tt * 8] = o;
}

// ---------------- pooling + FC + log_softmax ----------------

__global__ void k_bounds(const int* __restrict__ batch, int* __restrict__ gstart,
                         int* __restrict__ gend, int N) {
    int n = blockIdx.x * 256 + threadIdx.x;
    if (n < N) {
        int g = batch[n];
        if (n == 0 || batch[n - 1] != g) gstart[g] = n;
        if (n == N - 1 || batch[n + 1] != g) gend[g] = n + 1;
    }
}

#define PCHUNK 32
__global__ __launch_bounds__(256) void k_pool(const ushort* __restrict__ h,
                                              const int* __restrict__ batch,
                                              float* __restrict__ pooled, int N) {
    int c  = blockIdx.y * 256 + threadIdx.x;
    int n0 = blockIdx.x * PCHUNK;
    int n1 = n0 + PCHUNK; if (n1 > N) n1 = N;
    int g = batch[n0];
    float acc = 0.f;
    for (int n = n0; n < n1; ++n) {
        int gn = batch[n];
        if (gn != g) {
            atomicAdd(&pooled[g * HID + c], acc);
            acc = 0.f; g = gn;
        }
        acc += bf16f(h[(size_t)n * HID + c]);
    }
    atomicAdd(&pooled[g * HID + c], acc);
}

__global__ __launch_bounds__(256) void k_fc(const float* __restrict__ pooled,
                                            const int* __restrict__ gstart,
                                            const int* __restrict__ gend,
                                            const float* __restrict__ fcw,
                                            const float* __restrict__ fcb,
                                            float* __restrict__ out) {
    int g = blockIdx.x;
    int t = threadIdx.x;
    float invc = 1.f / fmaxf((float)(gend[g] - gstart[g]), 1.f);
    __shared__ float red[NCLS][256];
    float part[NCLS];
#pragma unroll
    for (int c = 0; c < NCLS; ++c) part[c] = 0.f;
    for (int k = t; k < HID; k += 256) {
        float v = pooled[g * HID + k] * invc;
#pragma unroll
        for (int c = 0; c < NCLS; ++c) part[c] += v * fcw[k * NCLS + c];
    }
#pragma unroll
    for (int c = 0; c < NCLS; ++c) red[c][t] = part[c];
    __syncthreads();
    for (int off = 128; off > 0; off >>= 1) {
        if (t < off) {
#pragma unroll
            for (int c = 0; c < NCLS; ++c) red[c][t] += red[c][t + off];
        }
        __syncthreads();
    }
    if (t == 0) {
        float logits[NCLS];
        float mx = -1e30f;
#pragma unroll
        for (int c = 0; c < NCLS; ++c) {
            logits[c] = red[c][0] + fcb[c];
            mx = fmaxf(mx, logits[c]);
        }
        float se = 0.f;
#pragma unroll
        for (int c = 0; c < NCLS; ++c) se += expf(logits[c] - mx);
        float lse = mx + logf(se);
#pragma unroll
        for (int c = 0; c < NCLS; ++c) out[g * NCLS + c] = logits[c] - lse;
    }
}

// ---------------- launch ----------------

extern "C" void kernel_launch(void* const* d_in, const int* in_sizes, int n_in,
                              void* d_out, int out_size, void* d_ws, size_t ws_size,
                              hipStream_t stream) {
    const float* x    = (const float*)d_in[0];
    const int*   ei   = (const int*)d_in[1];
    const int*   batch= (const int*)d_in[2];
    const float* W0   = (const float*)d_in[3];
    const float* W1   = (const float*)d_in[4];
    const float* W2   = (const float*)d_in[5];
    const float* asrc = (const float*)d_in[6];
    const float* adst = (const float*)d_in[7];
    const float* bias = (const float*)d_in[8];
    const float* fcw  = (const float*)d_in[9];
    const float* fcb  = (const float*)d_in[10];
    float* out = (float*)d_out;

    const int E = in_sizes[1] / 2;
    const int N = NNODES;
    const int NE = E + N;
    const int NEPAD = ((NE + 3) & ~3) + 16;
    const int NBM = (N + BM - 1) / BM;       // 79
    const int NWG = NBM * (HID / BN);        // 632, %8 == 0

    // workspace layout
    char* ws = (char*)d_ws;
    size_t off = 0;
    auto alloc = [&](size_t bytes) { void* p = ws + off; off += (bytes + 255) & ~(size_t)255; return p; };
    ushort* projb  = (ushort*)alloc((size_t)N * HID * 2);
    ushort* hb16   = (ushort*)alloc((size_t)N * HID * 2);
    ushort* xb16   = (ushort*)alloc((size_t)N * 512 * 2);
    ushort* w0t    = (ushort*)alloc((size_t)HID * 512 * 2);
    ushort* w1t    = (ushort*)alloc((size_t)HID * HID * 2);
    ushort* w2t    = (ushort*)alloc((size_t)HID * HID * 2);
    float*  alphaT = (float*)alloc((size_t)NEPAD * NHEADS * 4);
    int*    row_ptr= (int*)alloc((size_t)(N + 1) * 4);
    int*    col    = (int*)alloc((size_t)(NE + 16) * 4);
    // ---- contiguous zero region (single memset every call) ----
    size_t zstart = off;
    int*    counts  = (int*)alloc((size_t)N * 4);
    int*    fill    = (int*)alloc((size_t)N * 4);
    int*    gstart  = (int*)alloc(NGRAPH * 4);
    int*    gend    = (int*)alloc(NGRAPH * 4);
    float*  pooled  = (float*)alloc(NGRAPH * HID * 4);
    float*  esrcAll = (float*)alloc((size_t)3 * N * NHEADS * 4);
    float*  edstAll = (float*)alloc((size_t)3 * N * NHEADS * 4);
    size_t zbytes = off - zstart;
    (void)ws_size;

    const int* srcArr = ei;
    const int* dstArr = ei + E;

    hipMemsetAsync(ws + zstart, 0, zbytes, stream);
    hipMemsetAsync(col + NE, 0, 16 * 4, stream);   // sanitize padded col slots

    // CSR build
    int nbE = (NE + 255) / 256;
    k_hist<<<nbE, 256, 0, stream>>>(dstArr, counts, E);
    k_scan<<<1, 1024, 0, stream>>>(counts, row_ptr, N);
    k_scatter<<<nbE, 256, 0, stream>>>(srcArr, dstArr, row_ptr, fill, col, E);

    // conversions
    k_f32_to_bf16<<<(N * 512 / 4 + 255) / 256, 256, 0, stream>>>(x, xb16, N * 512 / 4);
    k_wT<<<dim3(32, 512 / 32), 256, 0, stream>>>(W0, w0t, 512);
    k_wT<<<dim3(32, HID / 32), 256, 0, stream>>>(W1, w1t, HID);
    k_wT<<<dim3(32, HID / 32), 256, 0, stream>>>(W2, w2t, HID);

    const int N4 = N * NHEADS;

    // layer 0
    k_gemm_bf16<<<NWG, 256, 0, stream>>>(xb16, w0t, projb, N, 512, NBM,
                                         asrc + 0 * HID, adst + 0 * HID,
                                         esrcAll + 0 * N4, edstAll + 0 * N4);
    k_alpha<<<N / 4, 256, 0, stream>>>(esrcAll + 0 * N4, edstAll + 0 * N4, row_ptr, col, alphaT, NEPAD);
    k_agg<<<N / 2, 256, 0, stream>>>(projb, alphaT, row_ptr, col, bias + 0 * HID, hb16, NEPAD);

    // layer 1
    k_gemm_bf16<<<NWG, 256, 0, stream>>>(hb16, w1t, projb, N, HID, NBM,
                                         asrc + 1 * HID, adst + 1 * HID,
                                         esrcAll + 1 * N4, edstAll + 1 * N4);
    k_alpha<<<N / 4, 256, 0, stream>>>(esrcAll + 1 * N4, edstAll + 1 * N4, row_ptr, col, alphaT, NEPAD);
    k_agg<<<N / 2, 256, 0, stream>>>(projb, alphaT, row_ptr, col, bias + 1 * HID, hb16, NEPAD);

    // layer 2
    k_gemm_bf16<<<NWG, 256, 0, stream>>>(hb16, w2t, projb, N, HID, NBM,
                                         asrc + 2 * HID, adst + 2 * HID,
                                         esrcAll + 2 * N4, edstAll + 2 * N4);
    k_alpha<<<N / 4, 256, 0, stream>>>(esrcAll + 2 * N4, edstAll + 2 * N4, row_ptr, col, alphaT, NEPAD);
    k_agg<<<N / 2, 256, 0, stream>>>(projb, alphaT, row_ptr, col, bias + 2 * HID, hb16, NEPAD);

    // pool + FC + log_softmax
    k_bounds<<<(N + 255) / 256, 256, 0, stream>>>(batch, gstart, gend, N);
    dim3 poolGrid((N + PCHUNK - 1) / PCHUNK, HID / 256);
    k_pool<<<poolGrid, 256, 0, stream>>>(hb16, batch, pooled, N);
    k_fc<<<NGRAPH, 256, 0, stream>>>(pooled, gstart, gend, fcw, fcb, out);
}

// Round 9
// 340.052 us; speedup vs baseline: 1.2042x; 1.2042x over previous
//
#include <hip/hip_runtime.h>
#include <math.h>

#define NNODES 10000
#define HID    1024
#define NHEADS 4
#define NGRAPH 16
#define NCLS   10

typedef __attribute__((ext_vector_type(8))) short bf16x8;
typedef __attribute__((ext_vector_type(8))) ushort u16x8;
typedef __attribute__((ext_vector_type(4))) float f32x4;

__device__ __forceinline__ ushort bf16r(float f) {
    union { float f; unsigned u; } x; x.f = f;
    unsigned r = x.u + 0x7FFFu + ((x.u >> 16) & 1u);
    return (ushort)(r >> 16);
}
__device__ __forceinline__ float bf16f(ushort u) {
    union { unsigned u; float f; } x; x.u = ((unsigned)u) << 16;
    return x.f;
}
__device__ __forceinline__ float leaky(float e) { return e > 0.f ? e : 0.2f * e; }

// ---------------- CSR build ----------------

__global__ void k_hist(const int* __restrict__ dstArr, int* __restrict__ counts, int E) {
    int e = blockIdx.x * 256 + threadIdx.x;
    int total = E + NNODES;
    if (e < total) {
        int d = (e < E) ? dstArr[e] : (e - E);   // self-loops appended
        atomicAdd(&counts[d], 1);
    }
}

__global__ __launch_bounds__(1024) void k_scan(const int* __restrict__ counts,
                                               int* __restrict__ row_ptr, int N) {
    __shared__ int lds[1024];
    int t = threadIdx.x;
    const int C = (N + 1023) / 1024;
    int base = t * C;
    int s = 0;
    for (int i = 0; i < C; ++i)
        if (base + i < N) s += counts[base + i];
    lds[t] = s;
    __syncthreads();
    for (int off = 1; off < 1024; off <<= 1) {
        int add = (t >= off) ? lds[t - off] : 0;
        __syncthreads();
        lds[t] += add;
        __syncthreads();
    }
    int run = lds[t] - s;   // exclusive prefix
    for (int i = 0; i < C; ++i) {
        if (base + i < N) {
            row_ptr[base + i] = run;
            run += counts[base + i];
        }
    }
    if (t == 1023) row_ptr[N] = lds[1023];
}

__global__ void k_scatter(const int* __restrict__ srcArr, const int* __restrict__ dstArr,
                          const int* __restrict__ row_ptr, int* __restrict__ fill,
                          int* __restrict__ col, int E) {
    int e = blockIdx.x * 256 + threadIdx.x;
    int total = E + NNODES;
    if (e < total) {
        int s, d;
        if (e < E) { s = srcArr[e]; d = dstArr[e]; }
        else       { s = d = e - E; }
        int pos = row_ptr[d] + atomicAdd(&fill[d], 1);
        col[pos] = s;
    }
}

// ---------------- conversions ----------------

__global__ void k_f32_to_bf16(const float* __restrict__ in, ushort* __restrict__ out, int n4) {
    int i = blockIdx.x * 256 + threadIdx.x;
    if (i < n4) {
        float4 v = ((const float4*)in)[i];
        ushort4 o;
        o.x = bf16r(v.x); o.y = bf16r(v.y); o.z = bf16r(v.z); o.w = bf16r(v.w);
        ((ushort4*)out)[i] = o;
    }
}

// W [K][1024] f32 -> Wt [1024][K] bf16
__global__ __launch_bounds__(256) void k_wT(const float* __restrict__ W, ushort* __restrict__ Wt, int K) {
    __shared__ ushort tile[32][33];
    int bx = blockIdx.x;              // along N (1024/32)
    int by = blockIdx.y;              // along K
    int tx = threadIdx.x & 31, ty = threadIdx.x >> 5;   // 32 x 8
#pragma unroll
    for (int i = 0; i < 32; i += 8) {
        int k  = by * 32 + ty + i;
        int nn = bx * 32 + tx;
        tile[ty + i][tx] = bf16r(W[(size_t)k * HID + nn]);
    }
    __syncthreads();
#pragma unroll
    for (int i = 0; i < 32; i += 8) {
        int nn = bx * 32 + ty + i;
        int k  = by * 32 + tx;
        Wt[(size_t)nn * K + k] = tile[tx][ty + i];
    }
}

// ---------------- bf16 MFMA GEMM: C[M,1024] = A[M,K] * Bt[1024,K]^T, bf16 out ----------------
// Round-7 proven structure (no epilogue fusion, plain 2D grid).
// Staging source pointers precomputed (loop-invariant except +k0).

#define BM 128
#define BN 128
#define BK 64

__global__ __launch_bounds__(256) void k_gemm_bf16(const ushort* __restrict__ A,
                                                   const ushort* __restrict__ Bt,
                                                   ushort* __restrict__ C, int M, int K) {
    __shared__ ushort As[BM * BK];
    __shared__ ushort Bs[BN * BK];
    const int t    = threadIdx.x;
    const int lane = t & 63;
    const int w    = t >> 6;
    const int wr   = w >> 1, wc = w & 1;
    const int bm   = blockIdx.y * BM;
    const int bn   = blockIdx.x * BN;

    f32x4 acc[4][4] = {};

    const int r_  = t >> 3;          // fc = i*256+t -> row = i*32 + t>>3
    const int cp_ = t & 7;           // linear chunk within row

    // precompute staging pointers (k0-invariant part)
    const ushort* aSrc[4];
    const ushort* bSrc[4];
#pragma unroll
    for (int i = 0; i < 4; ++i) {
        int r  = i * 32 + r_;
        int c  = cp_ ^ (r & 7);      // inverse-swizzled source chunk
        int ga = bm + r; if (ga >= M) ga = M - 1;
        aSrc[i] = &A[(size_t)ga * K + c * 8];
        bSrc[i] = &Bt[(size_t)(bn + r) * K + c * 8];
    }

    for (int k0 = 0; k0 < K; k0 += BK) {
        __syncthreads();             // LDS free for overwrite
#pragma unroll
        for (int i = 0; i < 4; ++i) {
            int fc = i * 256 + t;
            __builtin_amdgcn_global_load_lds(
                (const __attribute__((address_space(1))) unsigned*)(aSrc[i] + k0),
                (__attribute__((address_space(3))) unsigned*)&As[fc * 8], 16, 0, 0);
            __builtin_amdgcn_global_load_lds(
                (const __attribute__((address_space(1))) unsigned*)(bSrc[i] + k0),
                (__attribute__((address_space(3))) unsigned*)&Bs[fc * 8], 16, 0, 0);
        }
        __syncthreads();             // staging visible (compiler drains vmcnt)

#pragma unroll
        for (int s = 0; s < 2; ++s) {
            const int kc = s * 4 + (lane >> 4);     // k-chunk index 0..7
            bf16x8 a[4], b[4];
#pragma unroll
            for (int m = 0; m < 4; ++m) {
                int row = wr * 64 + m * 16 + (lane & 15);
                int ch  = kc ^ (row & 7);
                a[m] = *(const bf16x8*)&As[row * BK + ch * 8];
            }
#pragma unroll
            for (int n = 0; n < 4; ++n) {
                int cl = wc * 64 + n * 16 + (lane & 15);
                int ch = kc ^ (cl & 7);
                b[n] = *(const bf16x8*)&Bs[cl * BK + ch * 8];
            }
#pragma unroll
            for (int m = 0; m < 4; ++m)
#pragma unroll
                for (int n = 0; n < 4; ++n)
                    acc[m][n] = __builtin_amdgcn_mfma_f32_16x16x32_bf16(a[m], b[n], acc[m][n], 0, 0, 0);
        }
    }

    // C-write. C/D layout: col = lane&15, row = (lane>>4)*4 + j   [m89-verified]
#pragma unroll
    for (int m = 0; m < 4; ++m) {
        int row0 = bm + wr * 64 + m * 16 + (lane >> 4) * 4;
#pragma unroll
        for (int n = 0; n < 4; ++n) {
            int coln = bn + wc * 64 + n * 16 + (lane & 15);
#pragma unroll
            for (int j = 0; j < 4; ++j) {
                int row = row0 + j;
                if (row < M) C[(size_t)row * HID + coln] = bf16r(acc[m][n][j]);
            }
        }
    }
}

// ---------------- per-node attention scalars (bf16 proj) ----------------
// 1 wave per node, 4 nodes per block. lane covers 16 channels (32B).

__global__ __launch_bounds__(256) void k_edotv(const ushort* __restrict__ proj,
                                               const float* __restrict__ asrc,
                                               const float* __restrict__ adst,
                                               float* __restrict__ esrc,
                                               float* __restrict__ edst) {
    int lane = threadIdx.x & 63;
    int n = blockIdx.x * 4 + (threadIdx.x >> 6);
    int h = lane >> 4;                 // 16 lanes per head
    int c0 = lane * 16;
    u16x8 p0 = *(const u16x8*)&proj[(size_t)n * HID + c0];
    u16x8 p1 = *(const u16x8*)&proj[(size_t)n * HID + c0 + 8];
    float ds_ = 0.f, dd = 0.f;
#pragma unroll
    for (int i = 0; i < 8; ++i) {
        float v0 = bf16f(p0[i]), v1 = bf16f(p1[i]);
        ds_ += v0 * asrc[c0 + i] + v1 * asrc[c0 + 8 + i];
        dd  += v0 * adst[c0 + i] + v1 * adst[c0 + 8 + i];
    }
#pragma unroll
    for (int off = 8; off > 0; off >>= 1) {
        ds_ += __shfl_xor(ds_, off);
        dd  += __shfl_xor(dd, off);
    }
    if ((lane & 15) == 0) {
        esrc[n * NHEADS + h] = ds_;
        edst[n * NHEADS + h] = dd;
    }
}

// ---------------- per-edge normalized attention weights (transposed out) ----------------
// 1 wave per node, 4 nodes per block. Writes alphaT[h][csr_slot].

__global__ __launch_bounds__(256) void k_alpha(const float* __restrict__ esrc,
                                               const float* __restrict__ edst,
                                               const int* __restrict__ row_ptr,
                                               const int* __restrict__ col,
                                               float* __restrict__ alphaT, int nepad) {
    const int lane = threadIdx.x & 63;
    const int n = blockIdx.x * 4 + (threadIdx.x >> 6);
    const int beg = row_ptr[n], end = row_ptr[n + 1];
    const int deg = end - beg;
    const float4 ed = *(const float4*)&edst[n * 4];

    float e0[4], e1[4];
    const bool has0 = lane < deg;
    const bool has1 = lane + 64 < deg;
    float m0 = -1e30f, m1 = -1e30f, m2 = -1e30f, m3 = -1e30f;
    if (has0) {
        float4 es = *(const float4*)&esrc[col[beg + lane] * 4];
        e0[0] = leaky(es.x + ed.x); e0[1] = leaky(es.y + ed.y);
        e0[2] = leaky(es.z + ed.z); e0[3] = leaky(es.w + ed.w);
        m0 = e0[0]; m1 = e0[1]; m2 = e0[2]; m3 = e0[3];
    }
    if (has1) {
        float4 es = *(const float4*)&esrc[col[beg + 64 + lane] * 4];
        e1[0] = leaky(es.x + ed.x); e1[1] = leaky(es.y + ed.y);
        e1[2] = leaky(es.z + ed.z); e1[3] = leaky(es.w + ed.w);
        m0 = fmaxf(m0, e1[0]); m1 = fmaxf(m1, e1[1]);
        m2 = fmaxf(m2, e1[2]); m3 = fmaxf(m3, e1[3]);
    }
    for (int j = beg + 128 + lane; j < end; j += 64) {   // rare path
        float4 es = *(const float4*)&esrc[col[j] * 4];
        m0 = fmaxf(m0, leaky(es.x + ed.x)); m1 = fmaxf(m1, leaky(es.y + ed.y));
        m2 = fmaxf(m2, leaky(es.z + ed.z)); m3 = fmaxf(m3, leaky(es.w + ed.w));
    }
#pragma unroll
    for (int off = 32; off > 0; off >>= 1) {
        m0 = fmaxf(m0, __shfl_xor(m0, off)); m1 = fmaxf(m1, __shfl_xor(m1, off));
        m2 = fmaxf(m2, __shfl_xor(m2, off)); m3 = fmaxf(m3, __shfl_xor(m3, off));
    }
    float d0 = 0.f, d1 = 0.f, d2 = 0.f, d3 = 0.f;
    if (has0) {
        e0[0] = __expf(e0[0] - m0); e0[1] = __expf(e0[1] - m1);
        e0[2] = __expf(e0[2] - m2); e0[3] = __expf(e0[3] - m3);
        d0 += e0[0]; d1 += e0[1]; d2 += e0[2]; d3 += e0[3];
    }
    if (has1) {
        e1[0] = __expf(e1[0] - m0); e1[1] = __expf(e1[1] - m1);
        e1[2] = __expf(e1[2] - m2); e1[3] = __expf(e1[3] - m3);
        d0 += e1[0]; d1 += e1[1]; d2 += e1[2]; d3 += e1[3];
    }
    for (int j = beg + 128 + lane; j < end; j += 64) {   // rare path
        float4 es = *(const float4*)&esrc[col[j] * 4];
        d0 += __expf(leaky(es.x + ed.x) - m0); d1 += __expf(leaky(es.y + ed.y) - m1);
        d2 += __expf(leaky(es.z + ed.z) - m2); d3 += __expf(leaky(es.w + ed.w) - m3);
    }
#pragma unroll
    for (int off = 32; off > 0; off >>= 1) {
        d0 += __shfl_xor(d0, off); d1 += __shfl_xor(d1, off);
        d2 += __shfl_xor(d2, off); d3 += __shfl_xor(d3, off);
    }
    const float i0 = 1.f / d0, i1 = 1.f / d1, i2 = 1.f / d2, i3 = 1.f / d3;
    if (has0) {
        int j = beg + lane;
        alphaT[0 * nepad + j] = e0[0] * i0;
        alphaT[1 * nepad + j] = e0[1] * i1;
        alphaT[2 * nepad + j] = e0[2] * i2;
        alphaT[3 * nepad + j] = e0[3] * i3;
    }
    if (has1) {
        int j = beg + 64 + lane;
        alphaT[0 * nepad + j] = e1[0] * i0;
        alphaT[1 * nepad + j] = e1[1] * i1;
        alphaT[2 * nepad + j] = e1[2] * i2;
        alphaT[3 * nepad + j] = e1[3] * i3;
    }
    for (int j = beg + 128 + lane; j < end; j += 64) {   // rare path
        float4 es = *(const float4*)&esrc[col[j] * 4];
        alphaT[0 * nepad + j] = __expf(leaky(es.x + ed.x) - m0) * i0;
        alphaT[1 * nepad + j] = __expf(leaky(es.y + ed.y) - m1) * i1;
        alphaT[2 * nepad + j] = __expf(leaky(es.z + ed.z) - m2) * i2;
        alphaT[3 * nepad + j] = __expf(leaky(es.w + ed.w) - m3) * i3;
    }
}

// ---------------- aggregation: chunk-8 double-buffered gather ----------------
// 2 waves per node (128 threads x 8 ch), 2 nodes per 256-block.
// 8 row-gathers in flight while FMA-ing the previous 8.
// Macro internals use trailing-underscore names (round-6 shadowing lesson).

__global__ __launch_bounds__(256) void k_agg(const ushort* __restrict__ proj,
                                             const float* __restrict__ alphaT,
                                             const int* __restrict__ row_ptr,
                                             const int* __restrict__ col,
                                             const float* __restrict__ bias,
                                             ushort* __restrict__ hb16, int nepad) {
    const int half = threadIdx.x >> 7;
    const int nid  = blockIdx.x * 2 + half;
    const int tt   = threadIdx.x & 127;
    const int h    = tt >> 5;
    const int beg  = row_ptr[nid], end = row_ptr[nid + 1];
    const float* aT = alphaT + (size_t)h * nepad;
    const ushort* pbase = proj + tt * 8;

    float acc[8] = {};

#define LOADCHUNK(cb, A0, A1, A2, A3, V0, V1, V2, V3)                        \
    {                                                                        \
        int4   cc_ = *(const int4*)&col[cb];                                 \
        float4 aa_ = *(const float4*)&aT[cb];                                \
        bool m0_ = ((cb) + 0 >= beg) & ((cb) + 0 < end);                     \
        bool m1_ = ((cb) + 1 >= beg) & ((cb) + 1 < end);                     \
        bool m2_ = ((cb) + 2 >= beg) & ((cb) + 2 < end);                     \
        bool m3_ = ((cb) + 3 >= beg) & ((cb) + 3 < end);                     \
        int s0_ = m0_ ? cc_.x : 0; int s1_ = m1_ ? cc_.y : 0;                \
        int s2_ = m2_ ? cc_.z : 0; int s3_ = m3_ ? cc_.w : 0;                \
        A0 = m0_ ? aa_.x : 0.f; A1 = m1_ ? aa_.y : 0.f;                      \
        A2 = m2_ ? aa_.z : 0.f; A3 = m3_ ? aa_.w : 0.f;                      \
        V0 = *(const u16x8*)&pbase[(size_t)s0_ * HID];                       \
        V1 = *(const u16x8*)&pbase[(size_t)s1_ * HID];                       \
        V2 = *(const u16x8*)&pbase[(size_t)s2_ * HID];                       \
        V3 = *(const u16x8*)&pbase[(size_t)s3_ * HID];                       \
    }

#define FMACHUNK(A0, A1, A2, A3, V0, V1, V2, V3)                             \
    {                                                                        \
        _Pragma("unroll")                                                    \
        for (int i_ = 0; i_ < 8; ++i_)                                       \
            acc[i_] += A0 * bf16f(V0[i_]) + A1 * bf16f(V1[i_])               \
                     + A2 * bf16f(V2[i_]) + A3 * bf16f(V3[i_]);              \
    }

    int c = beg & ~7;
    float a0, a1, a2, a3, a4, a5, a6, a7;
    u16x8 v0, v1, v2, v3, v4, v5, v6, v7;
    LOADCHUNK(c,     a0, a1, a2, a3, v0, v1, v2, v3);
    LOADCHUNK(c + 4, a4, a5, a6, a7, v4, v5, v6, v7);
    for (c += 8; c < end; c += 8) {
        float na0, na1, na2, na3, na4, na5, na6, na7;
        u16x8 nv0, nv1, nv2, nv3, nv4, nv5, nv6, nv7;
        LOADCHUNK(c,     na0, na1, na2, na3, nv0, nv1, nv2, nv3);
        LOADCHUNK(c + 4, na4, na5, na6, na7, nv4, nv5, nv6, nv7);
        FMACHUNK(a0, a1, a2, a3, v0, v1, v2, v3);
        FMACHUNK(a4, a5, a6, a7, v4, v5, v6, v7);
        a0 = na0; a1 = na1; a2 = na2; a3 = na3;
        a4 = na4; a5 = na5; a6 = na6; a7 = na7;
        v0 = nv0; v1 = nv1; v2 = nv2; v3 = nv3;
        v4 = nv4; v5 = nv5; v6 = nv6; v7 = nv7;
    }
    FMACHUNK(a0, a1, a2, a3, v0, v1, v2, v3);
    FMACHUNK(a4, a5, a6, a7, v4, v5, v6, v7);
#undef LOADCHUNK
#undef FMACHUNK

    u16x8 o;
#pragma unroll
    for (int i = 0; i < 8; ++i) {
        float b = bias[tt * 8 + i];
        o[i] = bf16r(fmaxf(acc[i] + b, 0.f));
    }
    *(u16x8*)&hb16[(size_t)nid * HID + tt * 8] = o;
}

// ---------------- pooling + FC + log_softmax ----------------

__global__ void k_bounds(const int* __restrict__ batch, int* __restrict__ gstart,
                         int* __restrict__ gend, int N) {
    int n = blockIdx.x * 256 + threadIdx.x;
    if (n < N) {
        int g = batch[n];
        if (n == 0 || batch[n - 1] != g) gstart[g] = n;
        if (n == N - 1 || batch[n + 1] != g) gend[g] = n + 1;
    }
}

#define PCHUNK 32
__global__ __launch_bounds__(256) void k_pool(const ushort* __restrict__ h,
                                              const int* __restrict__ batch,
                                              float* __restrict__ pooled, int N) {
    int c  = blockIdx.y * 256 + threadIdx.x;
    int n0 = blockIdx.x * PCHUNK;
    int n1 = n0 + PCHUNK; if (n1 > N) n1 = N;
    int g = batch[n0];
    float acc = 0.f;
    for (int n = n0; n < n1; ++n) {
        int gn = batch[n];
        if (gn != g) {
            atomicAdd(&pooled[g * HID + c], acc);
            acc = 0.f; g = gn;
        }
        acc += bf16f(h[(size_t)n * HID + c]);
    }
    atomicAdd(&pooled[g * HID + c], acc);
}

__global__ __launch_bounds__(256) void k_fc(const float* __restrict__ pooled,
                                            const int* __restrict__ gstart,
                                            const int* __restrict__ gend,
                                            const float* __restrict__ fcw,
                                            const float* __restrict__ fcb,
                                            float* __restrict__ out) {
    int g = blockIdx.x;
    int t = threadIdx.x;
    float invc = 1.f / fmaxf((float)(gend[g] - gstart[g]), 1.f);
    __shared__ float red[NCLS][256];
    float part[NCLS];
#pragma unroll
    for (int c = 0; c < NCLS; ++c) part[c] = 0.f;
    for (int k = t; k < HID; k += 256) {
        float v = pooled[g * HID + k] * invc;
#pragma unroll
        for (int c = 0; c < NCLS; ++c) part[c] += v * fcw[k * NCLS + c];
    }
#pragma unroll
    for (int c = 0; c < NCLS; ++c) red[c][t] = part[c];
    __syncthreads();
    for (int off = 128; off > 0; off >>= 1) {
        if (t < off) {
#pragma unroll
            for (int c = 0; c < NCLS; ++c) red[c][t] += red[c][t + off];
        }
        __syncthreads();
    }
    if (t == 0) {
        float logits[NCLS];
        float mx = -1e30f;
#pragma unroll
        for (int c = 0; c < NCLS; ++c) {
            logits[c] = red[c][0] + fcb[c];
            mx = fmaxf(mx, logits[c]);
        }
        float se = 0.f;
#pragma unroll
        for (int c = 0; c < NCLS; ++c) se += expf(logits[c] - mx);
        float lse = mx + logf(se);
#pragma unroll
        for (int c = 0; c < NCLS; ++c) out[g * NCLS + c] = logits[c] - lse;
    }
}

// ---------------- launch ----------------

extern "C" void kernel_launch(void* const* d_in, const int* in_sizes, int n_in,
                              void* d_out, int out_size, void* d_ws, size_t ws_size,
                              hipStream_t stream) {
    const float* x    = (const float*)d_in[0];
    const int*   ei   = (const int*)d_in[1];
    const int*   batch= (const int*)d_in[2];
    const float* W0   = (const float*)d_in[3];
    const float* W1   = (const float*)d_in[4];
    const float* W2   = (const float*)d_in[5];
    const float* asrc = (const float*)d_in[6];
    const float* adst = (const float*)d_in[7];
    const float* bias = (const float*)d_in[8];
    const float* fcw  = (const float*)d_in[9];
    const float* fcb  = (const float*)d_in[10];
    float* out = (float*)d_out;

    const int E = in_sizes[1] / 2;
    const int N = NNODES;
    const int NE = E + N;
    const int NEPAD = ((NE + 3) & ~3) + 16;

    // workspace layout
    char* ws = (char*)d_ws;
    size_t off = 0;
    auto alloc = [&](size_t bytes) { void* p = ws + off; off += (bytes + 255) & ~(size_t)255; return p; };
    ushort* projb  = (ushort*)alloc((size_t)N * HID * 2);
    ushort* hb16   = (ushort*)alloc((size_t)N * HID * 2);
    ushort* xb16   = (ushort*)alloc((size_t)N * 512 * 2);
    ushort* w0t    = (ushort*)alloc((size_t)HID * 512 * 2);
    ushort* w1t    = (ushort*)alloc((size_t)HID * HID * 2);
    ushort* w2t    = (ushort*)alloc((size_t)HID * HID * 2);
    float*  esrc   = (float*)alloc((size_t)N * NHEADS * 4);
    float*  edst   = (float*)alloc((size_t)N * NHEADS * 4);
    float*  alphaT = (float*)alloc((size_t)NEPAD * NHEADS * 4);
    int*    row_ptr= (int*)alloc((size_t)(N + 1) * 4);
    int*    col    = (int*)alloc((size_t)(NE + 16) * 4);
    // ---- contiguous zero region (single memset every call) ----
    size_t zstart = off;
    int*    counts  = (int*)alloc((size_t)N * 4);
    int*    fill    = (int*)alloc((size_t)N * 4);
    int*    gstart  = (int*)alloc(NGRAPH * 4);
    int*    gend    = (int*)alloc(NGRAPH * 4);
    float*  pooled  = (float*)alloc(NGRAPH * HID * 4);
    size_t zbytes = off - zstart;
    (void)ws_size;

    const int* srcArr = ei;
    const int* dstArr = ei + E;

    hipMemsetAsync(ws + zstart, 0, zbytes, stream);
    hipMemsetAsync(col + NE, 0, 16 * 4, stream);   // sanitize padded col slots

    // CSR build
    int nbE = (NE + 255) / 256;
    k_hist<<<nbE, 256, 0, stream>>>(dstArr, counts, E);
    k_scan<<<1, 1024, 0, stream>>>(counts, row_ptr, N);
    k_scatter<<<nbE, 256, 0, stream>>>(srcArr, dstArr, row_ptr, fill, col, E);

    // conversions
    k_f32_to_bf16<<<(N * 512 / 4 + 255) / 256, 256, 0, stream>>>(x, xb16, N * 512 / 4);
    k_wT<<<dim3(32, 512 / 32), 256, 0, stream>>>(W0, w0t, 512);
    k_wT<<<dim3(32, HID / 32), 256, 0, stream>>>(W1, w1t, HID);
    k_wT<<<dim3(32, HID / 32), 256, 0, stream>>>(W2, w2t, HID);

    dim3 gemmGrid(HID / BN, (N + BM - 1) / BM);

    // layer 0
    k_gemm_bf16<<<gemmGrid, 256, 0, stream>>>(xb16, w0t, projb, N, 512);
    k_edotv<<<N / 4, 256, 0, stream>>>(projb, asrc + 0 * HID, adst + 0 * HID, esrc, edst);
    k_alpha<<<N / 4, 256, 0, stream>>>(esrc, edst, row_ptr, col, alphaT, NEPAD);
    k_agg<<<N / 2, 256, 0, stream>>>(projb, alphaT, row_ptr, col, bias + 0 * HID, hb16, NEPAD);

    // layer 1
    k_gemm_bf16<<<gemmGrid, 256, 0, stream>>>(hb16, w1t, projb, N, HID);
    k_edotv<<<N / 4, 256, 0, stream>>>(projb, asrc + 1 * HID, adst + 1 * HID, esrc, edst);
    k_alpha<<<N / 4, 256, 0, stream>>>(esrc, edst, row_ptr, col, alphaT, NEPAD);
    k_agg<<<N / 2, 256, 0, stream>>>(projb, alphaT, row_ptr, col, bias + 1 * HID, hb16, NEPAD);

    // layer 2
    k_gemm_bf16<<<gemmGrid, 256, 0, stream>>>(hb16, w2t, projb, N, HID);
    k_edotv<<<N / 4, 256, 0, stream>>>(projb, asrc + 2 * HID, adst + 2 * HID, esrc, edst);
    k_alpha<<<N / 4, 256, 0, stream>>>(esrc, edst, row_ptr, col, alphaT, NEPAD);
    k_agg<<<N / 2, 256, 0, stream>>>(projb, alphaT, row_ptr, col, bias + 2 * HID, hb16, NEPAD);

    // pool + FC + log_softmax
    k_bounds<<<(N + 255) / 256, 256, 0, stream>>>(batch, gstart, gend, N);
    dim3 poolGrid((N + PCHUNK - 1) / PCHUNK, HID / 256);
    k_pool<<<poolGrid, 256, 0, stream>>>(hb16, batch, pooled, N);
    k_fc<<<NGRAPH, 256, 0, stream>>>(pooled, gstart, gend, fcw, fcb, out);
}

// Round 10
// 294.070 us; speedup vs baseline: 1.3925x; 1.1564x over previous
//
#include <hip/hip_runtime.h>
#include <math.h>

#define NNODES 10000
#define HID    1024
#define NHEADS 4
#define NGRAPH 16
#define NCLS   10

typedef __attribute__((ext_vector_type(8))) short bf16x8;
typedef __attribute__((ext_vector_type(8))) ushort u16x8;
typedef __attribute__((ext_vector_type(4))) float f32x4;
typedef __attribute__((ext_vector_type(2))) float f32x2;

__device__ __forceinline__ ushort bf16r(float f) {
    union { float f; unsigned u; } x; x.f = f;
    unsigned r = x.u + 0x7FFFu + ((x.u >> 16) & 1u);
    return (ushort)(r >> 16);
}
__device__ __forceinline__ float bf16f(ushort u) {
    union { unsigned u; float f; } x; x.u = ((unsigned)u) << 16;
    return x.f;
}
__device__ __forceinline__ float leaky(float e) { return e > 0.f ? e : 0.2f * e; }

// ---------------- CSR build ----------------

__global__ void k_hist(const int* __restrict__ dstArr, int* __restrict__ counts, int E) {
    int e = blockIdx.x * 256 + threadIdx.x;
    int total = E + NNODES;
    if (e < total) {
        int d = (e < E) ? dstArr[e] : (e - E);   // self-loops appended
        atomicAdd(&counts[d], 1);
    }
}

__global__ __launch_bounds__(1024) void k_scan(const int* __restrict__ counts,
                                               int* __restrict__ row_ptr, int N) {
    __shared__ int lds[1024];
    int t = threadIdx.x;
    const int C = (N + 1023) / 1024;
    int base = t * C;
    int s = 0;
    for (int i = 0; i < C; ++i)
        if (base + i < N) s += counts[base + i];
    lds[t] = s;
    __syncthreads();
    for (int off = 1; off < 1024; off <<= 1) {
        int add = (t >= off) ? lds[t - off] : 0;
        __syncthreads();
        lds[t] += add;
        __syncthreads();
    }
    int run = lds[t] - s;   // exclusive prefix
    for (int i = 0; i < C; ++i) {
        if (base + i < N) {
            row_ptr[base + i] = run;
            run += counts[base + i];
        }
    }
    if (t == 1023) row_ptr[N] = lds[1023];
}

__global__ void k_scatter(const int* __restrict__ srcArr, const int* __restrict__ dstArr,
                          const int* __restrict__ row_ptr, int* __restrict__ fill,
                          int* __restrict__ col, int E) {
    int e = blockIdx.x * 256 + threadIdx.x;
    int total = E + NNODES;
    if (e < total) {
        int s, d;
        if (e < E) { s = srcArr[e]; d = dstArr[e]; }
        else       { s = d = e - E; }
        int pos = row_ptr[d] + atomicAdd(&fill[d], 1);
        col[pos] = s;
    }
}

// ---------------- conversions ----------------

__global__ void k_f32_to_bf16(const float* __restrict__ in, ushort* __restrict__ out, int n4) {
    int i = blockIdx.x * 256 + threadIdx.x;
    if (i < n4) {
        float4 v = ((const float4*)in)[i];
        ushort4 o;
        o.x = bf16r(v.x); o.y = bf16r(v.y); o.z = bf16r(v.z); o.w = bf16r(v.w);
        ((ushort4*)out)[i] = o;
    }
}

// W [K][1024] f32 -> Wt [1024][K] bf16
__global__ __launch_bounds__(256) void k_wT(const float* __restrict__ W, ushort* __restrict__ Wt, int K) {
    __shared__ ushort tile[32][33];
    int bx = blockIdx.x;              // along N (1024/32)
    int by = blockIdx.y;              // along K
    int tx = threadIdx.x & 31, ty = threadIdx.x >> 5;   // 32 x 8
#pragma unroll
    for (int i = 0; i < 32; i += 8) {
        int k  = by * 32 + ty + i;
        int nn = bx * 32 + tx;
        tile[ty + i][tx] = bf16r(W[(size_t)k * HID + nn]);
    }
    __syncthreads();
#pragma unroll
    for (int i = 0; i < 32; i += 8) {
        int nn = bx * 32 + ty + i;
        int k  = by * 32 + tx;
        Wt[(size_t)nn * K + k] = tile[tx][ty + i];
    }
}

// ---------------- bf16 MFMA GEMM: C[M,1024] = A[M,K] * Bt[1024,K]^T, bf16 out ----------------

#define BM 128
#define BN 128
#define BK 64

__global__ __launch_bounds__(256) void k_gemm_bf16(const ushort* __restrict__ A,
                                                   const ushort* __restrict__ Bt,
                                                   ushort* __restrict__ C, int M, int K) {
    __shared__ ushort As[BM * BK];
    __shared__ ushort Bs[BN * BK];
    const int t    = threadIdx.x;
    const int lane = t & 63;
    const int w    = t >> 6;
    const int wr   = w >> 1, wc = w & 1;
    const int bm   = blockIdx.y * BM;
    const int bn   = blockIdx.x * BN;

    f32x4 acc[4][4] = {};

    const int r_  = t >> 3;          // fc = i*256+t -> row = i*32 + t>>3
    const int cp_ = t & 7;           // linear chunk within row

    const ushort* aSrc[4];
    const ushort* bSrc[4];
#pragma unroll
    for (int i = 0; i < 4; ++i) {
        int r  = i * 32 + r_;
        int c  = cp_ ^ (r & 7);      // inverse-swizzled source chunk
        int ga = bm + r; if (ga >= M) ga = M - 1;
        aSrc[i] = &A[(size_t)ga * K + c * 8];
        bSrc[i] = &Bt[(size_t)(bn + r) * K + c * 8];
    }

    for (int k0 = 0; k0 < K; k0 += BK) {
        __syncthreads();
#pragma unroll
        for (int i = 0; i < 4; ++i) {
            int fc = i * 256 + t;
            __builtin_amdgcn_global_load_lds(
                (const __attribute__((address_space(1))) unsigned*)(aSrc[i] + k0),
                (__attribute__((address_space(3))) unsigned*)&As[fc * 8], 16, 0, 0);
            __builtin_amdgcn_global_load_lds(
                (const __attribute__((address_space(1))) unsigned*)(bSrc[i] + k0),
                (__attribute__((address_space(3))) unsigned*)&Bs[fc * 8], 16, 0, 0);
        }
        __syncthreads();

#pragma unroll
        for (int s = 0; s < 2; ++s) {
            const int kc = s * 4 + (lane >> 4);
            bf16x8 a[4], b[4];
#pragma unroll
            for (int m = 0; m < 4; ++m) {
                int row = wr * 64 + m * 16 + (lane & 15);
                int ch  = kc ^ (row & 7);
                a[m] = *(const bf16x8*)&As[row * BK + ch * 8];
            }
#pragma unroll
            for (int n = 0; n < 4; ++n) {
                int cl = wc * 64 + n * 16 + (lane & 15);
                int ch = kc ^ (cl & 7);
                b[n] = *(const bf16x8*)&Bs[cl * BK + ch * 8];
            }
#pragma unroll
            for (int m = 0; m < 4; ++m)
#pragma unroll
                for (int n = 0; n < 4; ++n)
                    acc[m][n] = __builtin_amdgcn_mfma_f32_16x16x32_bf16(a[m], b[n], acc[m][n], 0, 0, 0);
        }
    }

    // C/D layout: col = lane&15, row = (lane>>4)*4 + j   [m89-verified]
#pragma unroll
    for (int m = 0; m < 4; ++m) {
        int row0 = bm + wr * 64 + m * 16 + (lane >> 4) * 4;
#pragma unroll
        for (int n = 0; n < 4; ++n) {
            int coln = bn + wc * 64 + n * 16 + (lane & 15);
#pragma unroll
            for (int j = 0; j < 4; ++j) {
                int row = row0 + j;
                if (row < M) C[(size_t)row * HID + coln] = bf16r(acc[m][n][j]);
            }
        }
    }
}

// ---------------- per-node attention scalars + fp8 repack (bf16 proj in) ----------------
// 1 wave per node, 4 nodes per block. lane covers 16 contiguous channels.
// Also emits proj8 = fp8-e4m3 copy of proj for the gather kernel.

__global__ __launch_bounds__(256) void k_edotv(const ushort* __restrict__ proj,
                                               const float* __restrict__ asrc,
                                               const float* __restrict__ adst,
                                               float* __restrict__ esrc,
                                               float* __restrict__ edst,
                                               unsigned char* __restrict__ proj8) {
    int lane = threadIdx.x & 63;
    int n = blockIdx.x * 4 + (threadIdx.x >> 6);
    int h = lane >> 4;                 // 16 lanes per head
    int c0 = lane * 16;
    u16x8 p0 = *(const u16x8*)&proj[(size_t)n * HID + c0];
    u16x8 p1 = *(const u16x8*)&proj[(size_t)n * HID + c0 + 8];
    float f[16];
#pragma unroll
    for (int i = 0; i < 8; ++i) {
        f[i]     = bf16f((ushort)p0[i]);
        f[8 + i] = bf16f((ushort)p1[i]);
    }
    float ds_ = 0.f, dd = 0.f;
#pragma unroll
    for (int i = 0; i < 16; ++i) {
        ds_ += f[i] * asrc[c0 + i];
        dd  += f[i] * adst[c0 + i];
    }
    // fp8 pack: channels (q*4..q*4+3) -> one u32
    unsigned wv[4];
#pragma unroll
    for (int q = 0; q < 4; ++q) {
        int v = 0;
        v = __builtin_amdgcn_cvt_pk_fp8_f32(f[q * 4 + 0], f[q * 4 + 1], v, false);
        v = __builtin_amdgcn_cvt_pk_fp8_f32(f[q * 4 + 2], f[q * 4 + 3], v, true);
        wv[q] = (unsigned)v;
    }
    *(uint4*)(proj8 + (size_t)n * HID + c0) = make_uint4(wv[0], wv[1], wv[2], wv[3]);

#pragma unroll
    for (int off = 8; off > 0; off >>= 1) {
        ds_ += __shfl_xor(ds_, off);
        dd  += __shfl_xor(dd, off);
    }
    if ((lane & 15) == 0) {
        esrc[n * NHEADS + h] = ds_;
        edst[n * NHEADS + h] = dd;
    }
}

// ---------------- per-edge normalized attention weights (transposed out) ----------------
// 1 wave per node, 4 nodes per block. Writes alphaT[h][csr_slot].

__global__ __launch_bounds__(256) void k_alpha(const float* __restrict__ esrc,
                                               const float* __restrict__ edst,
                                               const int* __restrict__ row_ptr,
                                               const int* __restrict__ col,
                                               float* __restrict__ alphaT, int nepad) {
    const int lane = threadIdx.x & 63;
    const int n = blockIdx.x * 4 + (threadIdx.x >> 6);
    const int beg = row_ptr[n], end = row_ptr[n + 1];
    const int deg = end - beg;
    const float4 ed = *(const float4*)&edst[n * 4];

    float e0[4], e1[4];
    const bool has0 = lane < deg;
    const bool has1 = lane + 64 < deg;
    float m0 = -1e30f, m1 = -1e30f, m2 = -1e30f, m3 = -1e30f;
    if (has0) {
        float4 es = *(const float4*)&esrc[col[beg + lane] * 4];
        e0[0] = leaky(es.x + ed.x); e0[1] = leaky(es.y + ed.y);
        e0[2] = leaky(es.z + ed.z); e0[3] = leaky(es.w + ed.w);
        m0 = e0[0]; m1 = e0[1]; m2 = e0[2]; m3 = e0[3];
    }
    if (has1) {
        float4 es = *(const float4*)&esrc[col[beg + 64 + lane] * 4];
        e1[0] = leaky(es.x + ed.x); e1[1] = leaky(es.y + ed.y);
        e1[2] = leaky(es.z + ed.z); e1[3] = leaky(es.w + ed.w);
        m0 = fmaxf(m0, e1[0]); m1 = fmaxf(m1, e1[1]);
        m2 = fmaxf(m2, e1[2]); m3 = fmaxf(m3, e1[3]);
    }
    for (int j = beg + 128 + lane; j < end; j += 64) {   // rare path
        float4 es = *(const float4*)&esrc[col[j] * 4];
        m0 = fmaxf(m0, leaky(es.x + ed.x)); m1 = fmaxf(m1, leaky(es.y + ed.y));
        m2 = fmaxf(m2, leaky(es.z + ed.z)); m3 = fmaxf(m3, leaky(es.w + ed.w));
    }
#pragma unroll
    for (int off = 32; off > 0; off >>= 1) {
        m0 = fmaxf(m0, __shfl_xor(m0, off)); m1 = fmaxf(m1, __shfl_xor(m1, off));
        m2 = fmaxf(m2, __shfl_xor(m2, off)); m3 = fmaxf(m3, __shfl_xor(m3, off));
    }
    float d0 = 0.f, d1 = 0.f, d2 = 0.f, d3 = 0.f;
    if (has0) {
        e0[0] = __expf(e0[0] - m0); e0[1] = __expf(e0[1] - m1);
        e0[2] = __expf(e0[2] - m2); e0[3] = __expf(e0[3] - m3);
        d0 += e0[0]; d1 += e0[1]; d2 += e0[2]; d3 += e0[3];
    }
    if (has1) {
        e1[0] = __expf(e1[0] - m0); e1[1] = __expf(e1[1] - m1);
        e1[2] = __expf(e1[2] - m2); e1[3] = __expf(e1[3] - m3);
        d0 += e1[0]; d1 += e1[1]; d2 += e1[2]; d3 += e1[3];
    }
    for (int j = beg + 128 + lane; j < end; j += 64) {   // rare path
        float4 es = *(const float4*)&esrc[col[j] * 4];
        d0 += __expf(leaky(es.x + ed.x) - m0); d1 += __expf(leaky(es.y + ed.y) - m1);
        d2 += __expf(leaky(es.z + ed.z) - m2); d3 += __expf(leaky(es.w + ed.w) - m3);
    }
#pragma unroll
    for (int off = 32; off > 0; off >>= 1) {
        d0 += __shfl_xor(d0, off); d1 += __shfl_xor(d1, off);
        d2 += __shfl_xor(d2, off); d3 += __shfl_xor(d3, off);
    }
    const float i0 = 1.f / d0, i1 = 1.f / d1, i2 = 1.f / d2, i3 = 1.f / d3;
    if (has0) {
        int j = beg + lane;
        alphaT[0 * nepad + j] = e0[0] * i0;
        alphaT[1 * nepad + j] = e0[1] * i1;
        alphaT[2 * nepad + j] = e0[2] * i2;
        alphaT[3 * nepad + j] = e0[3] * i3;
    }
    if (has1) {
        int j = beg + 64 + lane;
        alphaT[0 * nepad + j] = e1[0] * i0;
        alphaT[1 * nepad + j] = e1[1] * i1;
        alphaT[2 * nepad + j] = e1[2] * i2;
        alphaT[3 * nepad + j] = e1[3] * i3;
    }
    for (int j = beg + 128 + lane; j < end; j += 64) {   // rare path
        float4 es = *(const float4*)&esrc[col[j] * 4];
        alphaT[0 * nepad + j] = __expf(leaky(es.x + ed.x) - m0) * i0;
        alphaT[1 * nepad + j] = __expf(leaky(es.y + ed.y) - m1) * i1;
        alphaT[2 * nepad + j] = __expf(leaky(es.z + ed.z) - m2) * i2;
        alphaT[3 * nepad + j] = __expf(leaky(es.w + ed.w) - m3) * i3;
    }
}

// ---------------- aggregation: fp8 chunk-8 double-buffered gather ----------------
// 2 waves per node (128 threads x 8 ch), 2 nodes per 256-block.
// 8B/lane/row fp8 gather, HW v_cvt_pk_f32_fp8 decode (1 inst / 2 channels).
// Macro internals use trailing-underscore names (round-6 shadowing lesson).

__global__ __launch_bounds__(256) void k_agg(const unsigned char* __restrict__ proj8,
                                             const float* __restrict__ alphaT,
                                             const int* __restrict__ row_ptr,
                                             const int* __restrict__ col,
                                             const float* __restrict__ bias,
                                             ushort* __restrict__ hb16, int nepad) {
    const int half = threadIdx.x >> 7;
    const int nid  = blockIdx.x * 2 + half;
    const int tt   = threadIdx.x & 127;
    const int h    = tt >> 5;
    const int beg  = row_ptr[nid], end = row_ptr[nid + 1];
    const float* aT = alphaT + (size_t)h * nepad;
    const unsigned char* pbase = proj8 + tt * 8;

    float acc[8] = {};

#define LOADCHUNK(cb, A0, A1, A2, A3, V0, V1, V2, V3)                        \
    {                                                                        \
        int4   cc_ = *(const int4*)&col[cb];                                 \
        float4 aa_ = *(const float4*)&aT[cb];                                \
        bool m0_ = ((cb) + 0 >= beg) & ((cb) + 0 < end);                     \
        bool m1_ = ((cb) + 1 >= beg) & ((cb) + 1 < end);                     \
        bool m2_ = ((cb) + 2 >= beg) & ((cb) + 2 < end);                     \
        bool m3_ = ((cb) + 3 >= beg) & ((cb) + 3 < end);                     \
        int s0_ = m0_ ? cc_.x : 0; int s1_ = m1_ ? cc_.y : 0;                \
        int s2_ = m2_ ? cc_.z : 0; int s3_ = m3_ ? cc_.w : 0;                \
        A0 = m0_ ? aa_.x : 0.f; A1 = m1_ ? aa_.y : 0.f;                      \
        A2 = m2_ ? aa_.z : 0.f; A3 = m3_ ? aa_.w : 0.f;                      \
        V0 = *(const uint2*)(pbase + (size_t)s0_ * HID);                     \
        V1 = *(const uint2*)(pbase + (size_t)s1_ * HID);                     \
        V2 = *(const uint2*)(pbase + (size_t)s2_ * HID);                     \
        V3 = *(const uint2*)(pbase + (size_t)s3_ * HID);                     \
    }

#define FMA1(A, V)                                                           \
    {                                                                        \
        f32x2 p01_ = __builtin_amdgcn_cvt_pk_f32_fp8(V.x, false);            \
        f32x2 p23_ = __builtin_amdgcn_cvt_pk_f32_fp8(V.x, true);             \
        f32x2 p45_ = __builtin_amdgcn_cvt_pk_f32_fp8(V.y, false);            \
        f32x2 p67_ = __builtin_amdgcn_cvt_pk_f32_fp8(V.y, true);             \
        acc[0] += A * p01_[0]; acc[1] += A * p01_[1];                        \
        acc[2] += A * p23_[0]; acc[3] += A * p23_[1];                        \
        acc[4] += A * p45_[0]; acc[5] += A * p45_[1];                        \
        acc[6] += A * p67_[0]; acc[7] += A * p67_[1];                        \
    }

#define FMACHUNK(A0, A1, A2, A3, V0, V1, V2, V3)                             \
    { FMA1(A0, V0) FMA1(A1, V1) FMA1(A2, V2) FMA1(A3, V3) }

    int c = beg & ~7;
    float a0, a1, a2, a3, a4, a5, a6, a7;
    uint2 v0, v1, v2, v3, v4, v5, v6, v7;
    LOADCHUNK(c,     a0, a1, a2, a3, v0, v1, v2, v3);
    LOADCHUNK(c + 4, a4, a5, a6, a7, v4, v5, v6, v7);
    for (c += 8; c < end; c += 8) {
        float na0, na1, na2, na3, na4, na5, na6, na7;
        uint2 nv0, nv1, nv2, nv3, nv4, nv5, nv6, nv7;
        LOADCHUNK(c,     na0, na1, na2, na3, nv0, nv1, nv2, nv3);
        LOADCHUNK(c + 4, na4, na5, na6, na7, nv4, nv5, nv6, nv7);
        FMACHUNK(a0, a1, a2, a3, v0, v1, v2, v3);
        FMACHUNK(a4, a5, a6, a7, v4, v5, v6, v7);
        a0 = na0; a1 = na1; a2 = na2; a3 = na3;
        a4 = na4; a5 = na5; a6 = na6; a7 = na7;
        v0 = nv0; v1 = nv1; v2 = nv2; v3 = nv3;
        v4 = nv4; v5 = nv5; v6 = nv6; v7 = nv7;
    }
    FMACHUNK(a0, a1, a2, a3, v0, v1, v2, v3);
    FMACHUNK(a4, a5, a6, a7, v4, v5, v6, v7);
#undef LOADCHUNK
#undef FMACHUNK
#undef FMA1

    u16x8 o;
#pragma unroll
    for (int i = 0; i < 8; ++i) {
        float b = bias[tt * 8 + i];
        o[i] = bf16r(fmaxf(acc[i] + b, 0.f));
    }
    *(u16x8*)&hb16[(size_t)nid * HID + tt * 8] = o;
}

// ---------------- pooling + FC + log_softmax ----------------

__global__ void k_bounds(const int* __restrict__ batch, int* __restrict__ gstart,
                         int* __restrict__ gend, int N) {
    int n = blockIdx.x * 256 + threadIdx.x;
    if (n < N) {
        int g = batch[n];
        if (n == 0 || batch[n - 1] != g) gstart[g] = n;
        if (n == N - 1 || batch[n + 1] != g) gend[g] = n + 1;
    }
}

#define PCHUNK 32
__global__ __launch_bounds__(256) void k_pool(const ushort* __restrict__ h,
                                              const int* __restrict__ batch,
                                              float* __restrict__ pooled, int N) {
    int c  = blockIdx.y * 256 + threadIdx.x;
    int n0 = blockIdx.x * PCHUNK;
    int n1 = n0 + PCHUNK; if (n1 > N) n1 = N;
    int g = batch[n0];
    float acc = 0.f;
    for (int n = n0; n < n1; ++n) {
        int gn = batch[n];
        if (gn != g) {
            atomicAdd(&pooled[g * HID + c], acc);
            acc = 0.f; g = gn;
        }
        acc += bf16f(h[(size_t)n * HID + c]);
    }
    atomicAdd(&pooled[g * HID + c], acc);
}

__global__ __launch_bounds__(256) void k_fc(const float* __restrict__ pooled,
                                            const int* __restrict__ gstart,
                                            const int* __restrict__ gend,
                                            const float* __restrict__ fcw,
                                            const float* __restrict__ fcb,
                                            float* __restrict__ out) {
    int g = blockIdx.x;
    int t = threadIdx.x;
    float invc = 1.f / fmaxf((float)(gend[g] - gstart[g]), 1.f);
    __shared__ float red[NCLS][256];
    float part[NCLS];
#pragma unroll
    for (int c = 0; c < NCLS; ++c) part[c] = 0.f;
    for (int k = t; k < HID; k += 256) {
        float v = pooled[g * HID + k] * invc;
#pragma unroll
        for (int c = 0; c < NCLS; ++c) part[c] += v * fcw[k * NCLS + c];
    }
#pragma unroll
    for (int c = 0; c < NCLS; ++c) red[c][t] = part[c];
    __syncthreads();
    for (int off = 128; off > 0; off >>= 1) {
        if (t < off) {
#pragma unroll
            for (int c = 0; c < NCLS; ++c) red[c][t] += red[c][t + off];
        }
        __syncthreads();
    }
    if (t == 0) {
        float logits[NCLS];
        float mx = -1e30f;
#pragma unroll
        for (int c = 0; c < NCLS; ++c) {
            logits[c] = red[c][0] + fcb[c];
            mx = fmaxf(mx, logits[c]);
        }
        float se = 0.f;
#pragma unroll
        for (int c = 0; c < NCLS; ++c) se += expf(logits[c] - mx);
        float lse = mx + logf(se);
#pragma unroll
        for (int c = 0; c < NCLS; ++c) out[g * NCLS + c] = logits[c] - lse;
    }
}

// ---------------- launch ----------------

extern "C" void kernel_launch(void* const* d_in, const int* in_sizes, int n_in,
                              void* d_out, int out_size, void* d_ws, size_t ws_size,
                              hipStream_t stream) {
    const float* x    = (const float*)d_in[0];
    const int*   ei   = (const int*)d_in[1];
    const int*   batch= (const int*)d_in[2];
    const float* W0   = (const float*)d_in[3];
    const float* W1   = (const float*)d_in[4];
    const float* W2   = (const float*)d_in[5];
    const float* asrc = (const float*)d_in[6];
    const float* adst = (const float*)d_in[7];
    const float* bias = (const float*)d_in[8];
    const float* fcw  = (const float*)d_in[9];
    const float* fcb  = (const float*)d_in[10];
    float* out = (float*)d_out;

    const int E = in_sizes[1] / 2;
    const int N = NNODES;
    const int NE = E + N;
    const int NEPAD = ((NE + 3) & ~3) + 16;

    // workspace layout
    char* ws = (char*)d_ws;
    size_t off = 0;
    auto alloc = [&](size_t bytes) { void* p = ws + off; off += (bytes + 255) & ~(size_t)255; return p; };
    ushort* projb  = (ushort*)alloc((size_t)N * HID * 2);
    unsigned char* proj8 = (unsigned char*)alloc((size_t)N * HID);
    ushort* hb16   = (ushort*)alloc((size_t)N * HID * 2);
    ushort* xb16   = (ushort*)alloc((size_t)N * 512 * 2);
    ushort* w0t    = (ushort*)alloc((size_t)HID * 512 * 2);
    ushort* w1t    = (ushort*)alloc((size_t)HID * HID * 2);
    ushort* w2t    = (ushort*)alloc((size_t)HID * HID * 2);
    float*  esrc   = (float*)alloc((size_t)N * NHEADS * 4);
    float*  edst   = (float*)alloc((size_t)N * NHEADS * 4);
    float*  alphaT = (float*)alloc((size_t)NEPAD * NHEADS * 4);
    int*    row_ptr= (int*)alloc((size_t)(N + 1) * 4);
    int*    col    = (int*)alloc((size_t)(NE + 16) * 4);
    // ---- contiguous zero region (single memset every call) ----
    size_t zstart = off;
    int*    counts  = (int*)alloc((size_t)N * 4);
    int*    fill    = (int*)alloc((size_t)N * 4);
    int*    gstart  = (int*)alloc(NGRAPH * 4);
    int*    gend    = (int*)alloc(NGRAPH * 4);
    float*  pooled  = (float*)alloc(NGRAPH * HID * 4);
    size_t zbytes = off - zstart;
    (void)ws_size;

    const int* srcArr = ei;
    const int* dstArr = ei + E;

    hipMemsetAsync(ws + zstart, 0, zbytes, stream);
    hipMemsetAsync(col + NE, 0, 16 * 4, stream);   // sanitize padded col slots

    // CSR build
    int nbE = (NE + 255) / 256;
    k_hist<<<nbE, 256, 0, stream>>>(dstArr, counts, E);
    k_scan<<<1, 1024, 0, stream>>>(counts, row_ptr, N);
    k_scatter<<<nbE, 256, 0, stream>>>(srcArr, dstArr, row_ptr, fill, col, E);

    // conversions
    k_f32_to_bf16<<<(N * 512 / 4 + 255) / 256, 256, 0, stream>>>(x, xb16, N * 512 / 4);
    k_wT<<<dim3(32, 512 / 32), 256, 0, stream>>>(W0, w0t, 512);
    k_wT<<<dim3(32, HID / 32), 256, 0, stream>>>(W1, w1t, HID);
    k_wT<<<dim3(32, HID / 32), 256, 0, stream>>>(W2, w2t, HID);

    dim3 gemmGrid(HID / BN, (N + BM - 1) / BM);

    // layer 0
    k_gemm_bf16<<<gemmGrid, 256, 0, stream>>>(xb16, w0t, projb, N, 512);
    k_edotv<<<N / 4, 256, 0, stream>>>(projb, asrc + 0 * HID, adst + 0 * HID, esrc, edst, proj8);
    k_alpha<<<N / 4, 256, 0, stream>>>(esrc, edst, row_ptr, col, alphaT, NEPAD);
    k_agg<<<N / 2, 256, 0, stream>>>(proj8, alphaT, row_ptr, col, bias + 0 * HID, hb16, NEPAD);

    // layer 1
    k_gemm_bf16<<<gemmGrid, 256, 0, stream>>>(hb16, w1t, projb, N, HID);
    k_edotv<<<N / 4, 256, 0, stream>>>(projb, asrc + 1 * HID, adst + 1 * HID, esrc, edst, proj8);
    k_alpha<<<N / 4, 256, 0, stream>>>(esrc, edst, row_ptr, col, alphaT, NEPAD);
    k_agg<<<N / 2, 256, 0, stream>>>(proj8, alphaT, row_ptr, col, bias + 1 * HID, hb16, NEPAD);

    // layer 2
    k_gemm_bf16<<<gemmGrid, 256, 0, stream>>>(hb16, w2t, projb, N, HID);
    k_edotv<<<N / 4, 256, 0, stream>>>(projb, asrc + 2 * HID, adst + 2 * HID, esrc, edst, proj8);
    k_alpha<<<N / 4, 256, 0, stream>>>(esrc, edst, row_ptr, col, alphaT, NEPAD);
    k_agg<<<N / 2, 256, 0, stream>>>(proj8, alphaT, row_ptr, col, bias + 2 * HID, hb16, NEPAD);

    // pool + FC + log_softmax
    k_bounds<<<(N + 255) / 256, 256, 0, stream>>>(batch, gstart, gend, N);
    dim3 poolGrid((N + PCHUNK - 1) / PCHUNK, HID / 256);
    k_pool<<<poolGrid, 256, 0, stream>>>(hb16, batch, pooled, N);
    k_fc<<<NGRAPH, 256, 0, stream>>>(pooled, gstart, gend, fcw, fcb, out);
}